// Round 5
// baseline (256.622 us; speedup 1.0000x reference)
//
#include <hip/hip_runtime.h>

#define NUM_K   512
#define DIM     64
#define N_ROWS  (32 * 64 * 64)     // 131072 rows
#define HW      4096               // 64*64
#define CHW     (64 * 4096)        // per-batch stride (C*H*W)

// Output buffer float32, flat layout = reference return order:
//   [ discrete (131072) | quantized NCHW (8388608) | loss (1) ]
#define IDX_OFF  0
#define Q_OFF    N_ROWS
#define LOSS_OFF (N_ROWS + 32 * 64 * 4096)   // 8519680

__global__ void vq_zero(double* __restrict__ loss_acc) {
    if (threadIdx.x == 0) *loss_acc = 0.0;
}

// numpy pairwise_sum (n=64, contiguous) of fl32(v[i]^2):
// 8 accumulators seeded from first 8 squares, 7 rounds of strided adds,
// combine ((r0+r1)+(r2+r3))+((r4+r5)+(r6+r7)). All ops single-rounded fp32.
#define NP_SUMSQ64(SRC, DST)                                                   \
    do {                                                                       \
        float r_[8];                                                           \
        _Pragma("unroll")                                                      \
        for (int j_ = 0; j_ < 8; ++j_) r_[j_] = __fmul_rn((SRC)[j_], (SRC)[j_]); \
        _Pragma("unroll")                                                      \
        for (int i_ = 8; i_ < 64; i_ += 8) {                                   \
            _Pragma("unroll")                                                  \
            for (int j_ = 0; j_ < 8; ++j_)                                     \
                r_[j_] = __fadd_rn(r_[j_], __fmul_rn((SRC)[i_ + j_], (SRC)[i_ + j_])); \
        }                                                                      \
        (DST) = __fadd_rn(__fadd_rn(__fadd_rn(r_[0], r_[1]), __fadd_rn(r_[2], r_[3])), \
                          __fadd_rn(__fadd_rn(r_[4], r_[5]), __fadd_rn(r_[6], r_[7]))); \
    } while (0)

__global__ __launch_bounds__(256) void vq_main(const float* __restrict__ x_in,
                                               const float* __restrict__ weight,
                                               double* __restrict__ loss_acc,
                                               float* __restrict__ out) {
    // ---- ||w_k||^2 table in LDS, numpy-pairwise-exact ----
    __shared__ float w2s[NUM_K];
    for (int k = threadIdx.x; k < NUM_K; k += 256) {
        const float* wk = weight + k * DIM;
        float s;
        NP_SUMSQ64(wk, s);
        w2s[k] = s;
    }
    __syncthreads();

    const int n  = blockIdx.x * 256 + threadIdx.x;   // row id
    const int b  = n >> 12;
    const int hw = n & 4095;

    // Load row's 64 features (coalesced: consecutive hw across lanes)
    const float* xp = x_in + b * CHW + hw;
    float x[DIM];
    #pragma unroll
    for (int d = 0; d < DIM; ++d) x[d] = xp[d * HW];

    // ---- A = np.sum(x*x) numpy-pairwise-exact ----
    float A;
    NP_SUMSQ64(x, A);

    // ---- distances: fl(fl(A - 2*M_k) + C_k), M_k = sequential fp32 FMA chain
    //      (OpenBLAS sgemm semantics). k unrolled x4 for ILP (chains independent).
    float best = 3.4e38f;
    int   bi   = 0;
    for (int k = 0; k < NUM_K; k += 4) {
        const float* w0 = weight + k * DIM;
        float m0 = 0.f, m1 = 0.f, m2 = 0.f, m3 = 0.f;
        #pragma unroll
        for (int d = 0; d < DIM; ++d) {
            float xd = x[d];
            m0 = __fmaf_rn(xd, w0[d],           m0);
            m1 = __fmaf_rn(xd, w0[DIM + d],     m1);
            m2 = __fmaf_rn(xd, w0[2 * DIM + d], m2);
            m3 = __fmaf_rn(xd, w0[3 * DIM + d], m3);
        }
        float d0 = __fadd_rn(__fsub_rn(A, __fmul_rn(2.0f, m0)), w2s[k]);
        float d1 = __fadd_rn(__fsub_rn(A, __fmul_rn(2.0f, m1)), w2s[k + 1]);
        float d2 = __fadd_rn(__fsub_rn(A, __fmul_rn(2.0f, m2)), w2s[k + 2]);
        float d3 = __fadd_rn(__fsub_rn(A, __fmul_rn(2.0f, m3)), w2s[k + 3]);
        // strict < sequentially: np.argmin first-min tie-break
        if (d0 < best) { best = d0; bi = k; }
        if (d1 < best) { best = d1; bi = k + 1; }
        if (d2 < best) { best = d2; bi = k + 2; }
        if (d3 < best) { best = d3; bi = k + 3; }
    }
    const int idx = bi;

    // ---- Outputs (float32) ----
    out[IDX_OFF + n] = (float)idx;

    const float* qrow = weight + idx * DIM;
    float* oq = out + Q_OFF + b * CHW + hw;   // quantized, NCHW
    float lsum = 0.0f;
    #pragma unroll
    for (int d = 0; d < DIM; ++d) {
        float xd   = x[d];
        float diff = __fsub_rn(qrow[d], xd);   // fl(q - x)
        float qst  = __fadd_rn(xd, diff);      // fl(x + fl(q - x)) = straight-through
        oq[d * HW] = qst;
        lsum = fmaf(diff, diff, lsum);         // loss tolerance is 2% — fused ok
    }

    // ---- Loss: wave shuffle -> LDS -> one f64 atomic per block ----
    #pragma unroll
    for (int off = 32; off > 0; off >>= 1) lsum += __shfl_down(lsum, off);
    __shared__ float wsum[4];
    int wave = threadIdx.x >> 6;
    if ((threadIdx.x & 63) == 0) wsum[wave] = lsum;
    __syncthreads();
    if (threadIdx.x == 0) {
        float bsum = (wsum[0] + wsum[1]) + (wsum[2] + wsum[3]);
        atomicAdd(loss_acc, (double)bsum);
    }
}

__global__ void vq_finalize(const double* __restrict__ loss_acc,
                            float* __restrict__ out) {
    double m = *loss_acc / 8388608.0;        // mean((q-x)^2)
    double loss = m + 0.25 * m;              // q_latent + 0.25 * e_latent
    out[LOSS_OFF] = (float)loss;
}

extern "C" void kernel_launch(void* const* d_in, const int* in_sizes, int n_in,
                              void* d_out, int out_size, void* d_ws, size_t ws_size,
                              hipStream_t stream) {
    const float* x = (const float*)d_in[0];    // inputs  [32,64,64,64] NCHW fp32
    const float* w = (const float*)d_in[1];    // weight  [512,64] fp32
    float* out = (float*)d_out;                // float32 output buffer
    double* loss_acc = (double*)d_ws;          // 8 bytes of ws only

    vq_zero<<<1, 64, 0, stream>>>(loss_acc);
    vq_main<<<N_ROWS / 256, 256, 0, stream>>>(x, w, loss_acc, out);
    vq_finalize<<<1, 1, 0, stream>>>(loss_acc, out);
}

// Round 6
// 247.974 us; speedup vs baseline: 1.0349x; 1.0349x over previous
//
#include <hip/hip_runtime.h>

#define NUM_K   512
#define DIM     64
#define N_ROWS  (32 * 64 * 64)     // 131072 rows
#define HW      4096               // 64*64
#define CHW     (64 * 4096)        // per-batch stride (C*H*W)

// Output buffer float32, flat layout = reference return order:
//   [ discrete (131072) | quantized NCHW (8388608) | loss (1) ]
#define IDX_OFF  0
#define Q_OFF    N_ROWS
#define LOSS_OFF (N_ROWS + 32 * 64 * 4096)   // 8519680

// numpy pairwise_sum (n=64, contiguous) of fl32(v[i]^2):
// 8 accumulators seeded from first 8 squares, 7 rounds of strided adds,
// combine ((r0+r1)+(r2+r3))+((r4+r5)+(r6+r7)). All ops single-rounded fp32.
// Validated bit-exact vs np reference in R5 (absmax 0.0).
#define NP_SUMSQ64(SRC, DST)                                                   \
    do {                                                                       \
        float r_[8];                                                           \
        _Pragma("unroll")                                                      \
        for (int j_ = 0; j_ < 8; ++j_) r_[j_] = __fmul_rn((SRC)[j_], (SRC)[j_]); \
        _Pragma("unroll")                                                      \
        for (int i_ = 8; i_ < 64; i_ += 8) {                                   \
            _Pragma("unroll")                                                  \
            for (int j_ = 0; j_ < 8; ++j_)                                     \
                r_[j_] = __fadd_rn(r_[j_], __fmul_rn((SRC)[i_ + j_], (SRC)[i_ + j_])); \
        }                                                                      \
        (DST) = __fadd_rn(__fadd_rn(__fadd_rn(r_[0], r_[1]), __fadd_rn(r_[2], r_[3])), \
                          __fadd_rn(__fadd_rn(r_[4], r_[5]), __fadd_rn(r_[6], r_[7]))); \
    } while (0)

// ---------------- split-k path ----------------
// Each block handles 256 rows x one code-chunk of `kpc` codes.
// grid = 512 * nchunks. Partial result per (row, chunk): u64 key
// (float bits of dist << 32) | code_idx  — dist is always ~64 > 0, so float
// bits are monotonic; min key == (min dist, then min idx) == numpy argmin.
__global__ __launch_bounds__(256, 4) void vq_partial(const float* __restrict__ x_in,
                                                     const float* __restrict__ weight,
                                                     unsigned long long* __restrict__ keys,
                                                     int kpc) {
    // ||w_k||^2 table in LDS, numpy-pairwise-exact (2 KB)
    __shared__ float w2s[NUM_K];
    for (int k = threadIdx.x; k < NUM_K; k += 256) {
        const float* wk = weight + k * DIM;
        float s;
        NP_SUMSQ64(wk, s);
        w2s[k] = s;
    }
    __syncthreads();

    const int rb    = blockIdx.x & 511;   // row-block
    const int chunk = blockIdx.x >> 9;    // code chunk
    const int n  = rb * 256 + threadIdx.x;
    const int b  = n >> 12;
    const int hw = n & 4095;

    const float* xp = x_in + b * CHW + hw;
    float x[DIM];
    #pragma unroll
    for (int d = 0; d < DIM; ++d) x[d] = xp[d * HW];
    // Pin x[] in VGPRs: opaque to the compiler -> no remat of the global loads
    #pragma unroll
    for (int d = 0; d < DIM; ++d) asm volatile("" : "+v"(x[d]));

    float A;
    NP_SUMSQ64(x, A);

    const int k0 = chunk * kpc;
    float best = 3.4e38f;
    int   bi   = k0;
    for (int k = k0; k < k0 + kpc; k += 4) {
        const float* w0 = weight + k * DIM;    // wave-uniform -> scalar loads
        float m0 = 0.f, m1 = 0.f, m2 = 0.f, m3 = 0.f;
        #pragma unroll
        for (int d = 0; d < DIM; ++d) {
            float xd = x[d];
            m0 = __fmaf_rn(xd, w0[d],           m0);
            m1 = __fmaf_rn(xd, w0[DIM + d],     m1);
            m2 = __fmaf_rn(xd, w0[2 * DIM + d], m2);
            m3 = __fmaf_rn(xd, w0[3 * DIM + d], m3);
        }
        float d0 = __fadd_rn(__fsub_rn(A, __fmul_rn(2.0f, m0)), w2s[k]);
        float d1 = __fadd_rn(__fsub_rn(A, __fmul_rn(2.0f, m1)), w2s[k + 1]);
        float d2 = __fadd_rn(__fsub_rn(A, __fmul_rn(2.0f, m2)), w2s[k + 2]);
        float d3 = __fadd_rn(__fsub_rn(A, __fmul_rn(2.0f, m3)), w2s[k + 3]);
        if (d0 < best) { best = d0; bi = k; }
        if (d1 < best) { best = d1; bi = k + 1; }
        if (d2 < best) { best = d2; bi = k + 2; }
        if (d3 < best) { best = d3; bi = k + 3; }
    }

    unsigned long long key =
        ((unsigned long long)__float_as_uint(best) << 32) | (unsigned)bi;
    keys[(size_t)chunk * N_ROWS + n] = key;
}

// Reduce partials, emit idx + quantized, per-block loss slot (no atomics/init).
__global__ __launch_bounds__(256) void vq_emit(const float* __restrict__ x_in,
                                               const float* __restrict__ weight,
                                               const unsigned long long* __restrict__ keys,
                                               double* __restrict__ lslots,
                                               float* __restrict__ out,
                                               int nchunks) {
    const int n = blockIdx.x * 256 + threadIdx.x;
    unsigned long long kk = keys[n];
    for (int c = 1; c < nchunks; ++c) {
        unsigned long long t = keys[(size_t)c * N_ROWS + n];
        if (t < kk) kk = t;
    }
    const int idx = (int)(kk & 0xffffffffu);
    out[IDX_OFF + n] = (float)idx;

    const int b  = n >> 12;
    const int hw = n & 4095;
    const float* xp   = x_in + b * CHW + hw;
    const float* qrow = weight + idx * DIM;
    float* oq = out + Q_OFF + b * CHW + hw;

    float lsum = 0.0f;
    #pragma unroll
    for (int d = 0; d < DIM; ++d) {
        float xd   = xp[d * HW];
        float diff = __fsub_rn(qrow[d], xd);   // fl(q - x)
        oq[d * HW] = __fadd_rn(xd, diff);      // straight-through
        lsum = fmaf(diff, diff, lsum);         // loss tol 2% — fused ok
    }

    #pragma unroll
    for (int off = 32; off > 0; off >>= 1) lsum += __shfl_down(lsum, off);
    __shared__ float wsum[4];
    if ((threadIdx.x & 63) == 0) wsum[threadIdx.x >> 6] = lsum;
    __syncthreads();
    if (threadIdx.x == 0)
        lslots[blockIdx.x] = (double)((wsum[0] + wsum[1]) + (wsum[2] + wsum[3]));
}

__global__ void vq_finalize2(const double* __restrict__ lslots,
                             float* __restrict__ out) {
    // 64 lanes x 8 slots each = 512
    double s = 0.0;
    for (int i = threadIdx.x; i < 512; i += 64) s += lslots[i];
    #pragma unroll
    for (int off = 32; off > 0; off >>= 1) s += __shfl_down(s, off);
    if (threadIdx.x == 0) {
        double m = s / 8388608.0;
        out[LOSS_OFF] = (float)(m + 0.25 * m);
    }
}

// ---------------- fallback (R5-validated fused path, used only if ws tiny) ----
__global__ void vq_zero(double* __restrict__ loss_acc) {
    if (threadIdx.x == 0) *loss_acc = 0.0;
}

__global__ __launch_bounds__(256) void vq_fused(const float* __restrict__ x_in,
                                                const float* __restrict__ weight,
                                                double* __restrict__ loss_acc,
                                                float* __restrict__ out) {
    __shared__ float w2s[NUM_K];
    for (int k = threadIdx.x; k < NUM_K; k += 256) {
        const float* wk = weight + k * DIM;
        float s;
        NP_SUMSQ64(wk, s);
        w2s[k] = s;
    }
    __syncthreads();

    const int n  = blockIdx.x * 256 + threadIdx.x;
    const int b  = n >> 12;
    const int hw = n & 4095;
    const float* xp = x_in + b * CHW + hw;
    float x[DIM];
    #pragma unroll
    for (int d = 0; d < DIM; ++d) x[d] = xp[d * HW];
    #pragma unroll
    for (int d = 0; d < DIM; ++d) asm volatile("" : "+v"(x[d]));

    float A;
    NP_SUMSQ64(x, A);

    float best = 3.4e38f;
    int   bi   = 0;
    for (int k = 0; k < NUM_K; k += 4) {
        const float* w0 = weight + k * DIM;
        float m0 = 0.f, m1 = 0.f, m2 = 0.f, m3 = 0.f;
        #pragma unroll
        for (int d = 0; d < DIM; ++d) {
            float xd = x[d];
            m0 = __fmaf_rn(xd, w0[d],           m0);
            m1 = __fmaf_rn(xd, w0[DIM + d],     m1);
            m2 = __fmaf_rn(xd, w0[2 * DIM + d], m2);
            m3 = __fmaf_rn(xd, w0[3 * DIM + d], m3);
        }
        float d0 = __fadd_rn(__fsub_rn(A, __fmul_rn(2.0f, m0)), w2s[k]);
        float d1 = __fadd_rn(__fsub_rn(A, __fmul_rn(2.0f, m1)), w2s[k + 1]);
        float d2 = __fadd_rn(__fsub_rn(A, __fmul_rn(2.0f, m2)), w2s[k + 2]);
        float d3 = __fadd_rn(__fsub_rn(A, __fmul_rn(2.0f, m3)), w2s[k + 3]);
        if (d0 < best) { best = d0; bi = k; }
        if (d1 < best) { best = d1; bi = k + 1; }
        if (d2 < best) { best = d2; bi = k + 2; }
        if (d3 < best) { best = d3; bi = k + 3; }
    }
    const int idx = bi;

    out[IDX_OFF + n] = (float)idx;
    const float* qrow = weight + idx * DIM;
    float* oq = out + Q_OFF + b * CHW + hw;
    float lsum = 0.0f;
    #pragma unroll
    for (int d = 0; d < DIM; ++d) {
        float xd   = x[d];
        float diff = __fsub_rn(qrow[d], xd);
        oq[d * HW] = __fadd_rn(xd, diff);
        lsum = fmaf(diff, diff, lsum);
    }
    #pragma unroll
    for (int off = 32; off > 0; off >>= 1) lsum += __shfl_down(lsum, off);
    __shared__ float wsum[4];
    if ((threadIdx.x & 63) == 0) wsum[threadIdx.x >> 6] = lsum;
    __syncthreads();
    if (threadIdx.x == 0)
        atomicAdd(loss_acc, (double)((wsum[0] + wsum[1]) + (wsum[2] + wsum[3])));
}

__global__ void vq_finalize(const double* __restrict__ loss_acc,
                            float* __restrict__ out) {
    double m = *loss_acc / 8388608.0;
    out[LOSS_OFF] = (float)(m + 0.25 * m);
}

extern "C" void kernel_launch(void* const* d_in, const int* in_sizes, int n_in,
                              void* d_out, int out_size, void* d_ws, size_t ws_size,
                              hipStream_t stream) {
    const float* x = (const float*)d_in[0];    // inputs  [32,64,64,64] NCHW fp32
    const float* w = (const float*)d_in[1];    // weight  [512,64] fp32
    float* out = (float*)d_out;

    int nchunks = 0;
    for (int c = 4; c >= 1; c >>= 1) {
        size_t need = (size_t)c * N_ROWS * 8 + 512 * 8;
        if (ws_size >= need) { nchunks = c; break; }
    }

    if (nchunks > 0) {
        unsigned long long* keys = (unsigned long long*)d_ws;
        double* lslots = (double*)((char*)d_ws + (size_t)nchunks * N_ROWS * 8);
        vq_partial<<<512 * nchunks, 256, 0, stream>>>(x, w, keys, NUM_K / nchunks);
        vq_emit<<<512, 256, 0, stream>>>(x, w, keys, lslots, out, nchunks);
        vq_finalize2<<<1, 64, 0, stream>>>(lslots, out);
    } else {
        double* loss_acc = (double*)d_ws;      // 8 bytes
        vq_zero<<<1, 64, 0, stream>>>(loss_acc);
        vq_fused<<<512, 256, 0, stream>>>(x, w, loss_acc, out);
        vq_finalize<<<1, 1, 0, stream>>>(loss_acc, out);
    }
}

// Round 7
// 229.091 us; speedup vs baseline: 1.1202x; 1.0824x over previous
//
#include <hip/hip_runtime.h>

#define NUM_K   512
#define DIM     64
#define N_ROWS  (32 * 64 * 64)     // 131072 rows
#define HW      4096               // 64*64
#define CHW     (64 * 4096)        // per-batch stride (C*H*W)
#define KPC     128                // codes per chunk (nchunks = 4)
#define NCHUNK  4

// Output buffer float32, flat layout = reference return order:
//   [ discrete (131072) | quantized NCHW (8388608) | loss (1) ]
#define IDX_OFF  0
#define Q_OFF    N_ROWS
#define LOSS_OFF (N_ROWS + 32 * 64 * 4096)   // 8519680

// numpy pairwise_sum (n=64) of squares — array form (validated bit-exact R5/R6)
#define NP_SUMSQ64(SRC, DST)                                                   \
    do {                                                                       \
        float r_[8];                                                           \
        _Pragma("unroll")                                                      \
        for (int j_ = 0; j_ < 8; ++j_) r_[j_] = __fmul_rn((SRC)[j_], (SRC)[j_]); \
        _Pragma("unroll")                                                      \
        for (int i_ = 8; i_ < 64; i_ += 8) {                                   \
            _Pragma("unroll")                                                  \
            for (int j_ = 0; j_ < 8; ++j_)                                     \
                r_[j_] = __fadd_rn(r_[j_], __fmul_rn((SRC)[i_ + j_], (SRC)[i_ + j_])); \
        }                                                                      \
        (DST) = __fadd_rn(__fadd_rn(__fadd_rn(r_[0], r_[1]), __fadd_rn(r_[2], r_[3])), \
                          __fadd_rn(__fadd_rn(r_[4], r_[5]), __fadd_rn(r_[6], r_[7]))); \
    } while (0)

#define SQ(v) __fmul_rn((v), (v))

// ---------------- split-k main kernel ----------------
// grid = 512 row-blocks * 4 code-chunks. Key = (dist_bits<<32)|idx, min-key
// == (min dist, first idx) == numpy argmin (validated R6).
__global__ __launch_bounds__(256, 4) void vq_partial(const float* __restrict__ x_in,
                                                     const float* __restrict__ weight,
                                                     unsigned long long* __restrict__ keys) {
    __shared__ float wlds[KPC * DIM];   // 32 KB: this chunk's codebook rows
    __shared__ float w2s[KPC];

    const int rb    = blockIdx.x & 511;   // row-block
    const int chunk = blockIdx.x >> 9;    // code chunk
    const int k0    = chunk * KPC;

    // ---- stage chunk weights into LDS (coalesced float4, one-shot) ----
    {
        const float4* src = (const float4*)(weight + k0 * DIM);
        float4* dst = (float4*)wlds;
        #pragma unroll
        for (int i = 0; i < (KPC * DIM / 4) / 256; ++i)
            dst[i * 256 + threadIdx.x] = src[i * 256 + threadIdx.x];
    }
    // ---- ||w_k||^2 for this chunk, numpy-pairwise-exact, from global (L2-hot) ----
    if (threadIdx.x < KPC) {
        const float* wk = weight + (k0 + threadIdx.x) * DIM;
        float s;
        NP_SUMSQ64(wk, s);
        w2s[threadIdx.x] = s;
    }
    __syncthreads();

    const int n  = rb * 256 + threadIdx.x;
    const int b  = n >> 12;
    const int hw = n & 4095;
    const float* xp = x_in + b * CHW + hw;

    // ---- x row in 16 named float4 locals (forces VGPR residency) ----
#define LD4(J) float4 X##J = make_float4(xp[(4*J+0)*HW], xp[(4*J+1)*HW], \
                                         xp[(4*J+2)*HW], xp[(4*J+3)*HW]);
    LD4(0)  LD4(1)  LD4(2)  LD4(3)  LD4(4)  LD4(5)  LD4(6)  LD4(7)
    LD4(8)  LD4(9)  LD4(10) LD4(11) LD4(12) LD4(13) LD4(14) LD4(15)
#undef LD4
#define PIN(J) asm volatile("" : "+v"(X##J.x), "+v"(X##J.y), "+v"(X##J.z), "+v"(X##J.w));
    PIN(0)  PIN(1)  PIN(2)  PIN(3)  PIN(4)  PIN(5)  PIN(6)  PIN(7)
    PIN(8)  PIN(9)  PIN(10) PIN(11) PIN(12) PIN(13) PIN(14) PIN(15)
#undef PIN

    // ---- A = np.sum(x*x): numpy 8-accumulator pairwise, element order 0..63 ----
    float A;
    {
        float r0 = SQ(X0.x), r1 = SQ(X0.y), r2 = SQ(X0.z), r3 = SQ(X0.w);
        float r4 = SQ(X1.x), r5 = SQ(X1.y), r6 = SQ(X1.z), r7 = SQ(X1.w);
#define ACC8(Xa, Xb)                                                  \
        r0 = __fadd_rn(r0, SQ(Xa.x)); r1 = __fadd_rn(r1, SQ(Xa.y));  \
        r2 = __fadd_rn(r2, SQ(Xa.z)); r3 = __fadd_rn(r3, SQ(Xa.w));  \
        r4 = __fadd_rn(r4, SQ(Xb.x)); r5 = __fadd_rn(r5, SQ(Xb.y));  \
        r6 = __fadd_rn(r6, SQ(Xb.z)); r7 = __fadd_rn(r7, SQ(Xb.w));
        ACC8(X2,  X3)  ACC8(X4,  X5)  ACC8(X6,  X7)
        ACC8(X8,  X9)  ACC8(X10, X11) ACC8(X12, X13) ACC8(X14, X15)
#undef ACC8
        A = __fadd_rn(__fadd_rn(__fadd_rn(r0, r1), __fadd_rn(r2, r3)),
                      __fadd_rn(__fadd_rn(r4, r5), __fadd_rn(r6, r7)));
    }

    // ---- scores: 4 codes at a time, weights via LDS broadcast (ds_read_b128) ----
    float best = 3.4e38f;
    int   bi   = k0;
    for (int kk = 0; kk < KPC; kk += 4) {
        const float4* wr0 = (const float4*)(wlds + (kk + 0) * DIM);
        const float4* wr1 = (const float4*)(wlds + (kk + 1) * DIM);
        const float4* wr2 = (const float4*)(wlds + (kk + 2) * DIM);
        const float4* wr3 = (const float4*)(wlds + (kk + 3) * DIM);
        float m0 = 0.f, m1 = 0.f, m2 = 0.f, m3 = 0.f;
        // sequential d-chain per code (OpenBLAS sgemm semantics, bit-exact R6)
#define STEP(J, XV)                                                        \
        { float4 wa = wr0[J], wb = wr1[J], wc = wr2[J], wd = wr3[J];       \
          m0 = __fmaf_rn(XV.x, wa.x, m0); m0 = __fmaf_rn(XV.y, wa.y, m0); \
          m0 = __fmaf_rn(XV.z, wa.z, m0); m0 = __fmaf_rn(XV.w, wa.w, m0); \
          m1 = __fmaf_rn(XV.x, wb.x, m1); m1 = __fmaf_rn(XV.y, wb.y, m1); \
          m1 = __fmaf_rn(XV.z, wb.z, m1); m1 = __fmaf_rn(XV.w, wb.w, m1); \
          m2 = __fmaf_rn(XV.x, wc.x, m2); m2 = __fmaf_rn(XV.y, wc.y, m2); \
          m2 = __fmaf_rn(XV.z, wc.z, m2); m2 = __fmaf_rn(XV.w, wc.w, m2); \
          m3 = __fmaf_rn(XV.x, wd.x, m3); m3 = __fmaf_rn(XV.y, wd.y, m3); \
          m3 = __fmaf_rn(XV.z, wd.z, m3); m3 = __fmaf_rn(XV.w, wd.w, m3); }
        STEP(0,  X0)  STEP(1,  X1)  STEP(2,  X2)  STEP(3,  X3)
        STEP(4,  X4)  STEP(5,  X5)  STEP(6,  X6)  STEP(7,  X7)
        STEP(8,  X8)  STEP(9,  X9)  STEP(10, X10) STEP(11, X11)
        STEP(12, X12) STEP(13, X13) STEP(14, X14) STEP(15, X15)
#undef STEP
        float d0 = __fadd_rn(__fsub_rn(A, __fmul_rn(2.0f, m0)), w2s[kk]);
        float d1 = __fadd_rn(__fsub_rn(A, __fmul_rn(2.0f, m1)), w2s[kk + 1]);
        float d2 = __fadd_rn(__fsub_rn(A, __fmul_rn(2.0f, m2)), w2s[kk + 2]);
        float d3 = __fadd_rn(__fsub_rn(A, __fmul_rn(2.0f, m3)), w2s[kk + 3]);
        if (d0 < best) { best = d0; bi = k0 + kk; }
        if (d1 < best) { best = d1; bi = k0 + kk + 1; }
        if (d2 < best) { best = d2; bi = k0 + kk + 2; }
        if (d3 < best) { best = d3; bi = k0 + kk + 3; }
    }

    keys[(size_t)chunk * N_ROWS + n] =
        ((unsigned long long)__float_as_uint(best) << 32) | (unsigned)bi;
}

// Reduce partials, emit idx + quantized, per-block loss slot (validated R6).
__global__ __launch_bounds__(256) void vq_emit(const float* __restrict__ x_in,
                                               const float* __restrict__ weight,
                                               const unsigned long long* __restrict__ keys,
                                               double* __restrict__ lslots,
                                               float* __restrict__ out,
                                               int nchunks) {
    const int n = blockIdx.x * 256 + threadIdx.x;
    unsigned long long kk = keys[n];
    for (int c = 1; c < nchunks; ++c) {
        unsigned long long t = keys[(size_t)c * N_ROWS + n];
        if (t < kk) kk = t;
    }
    const int idx = (int)(kk & 0xffffffffu);
    out[IDX_OFF + n] = (float)idx;

    const int b  = n >> 12;
    const int hw = n & 4095;
    const float* xp   = x_in + b * CHW + hw;
    const float* qrow = weight + idx * DIM;
    float* oq = out + Q_OFF + b * CHW + hw;

    float lsum = 0.0f;
    #pragma unroll
    for (int d = 0; d < DIM; ++d) {
        float xd   = xp[d * HW];
        float diff = __fsub_rn(qrow[d], xd);   // fl(q - x)
        oq[d * HW] = __fadd_rn(xd, diff);      // straight-through
        lsum = fmaf(diff, diff, lsum);         // loss tol 2% — fused ok
    }

    #pragma unroll
    for (int off = 32; off > 0; off >>= 1) lsum += __shfl_down(lsum, off);
    __shared__ float wsum[4];
    if ((threadIdx.x & 63) == 0) wsum[threadIdx.x >> 6] = lsum;
    __syncthreads();
    if (threadIdx.x == 0)
        lslots[blockIdx.x] = (double)((wsum[0] + wsum[1]) + (wsum[2] + wsum[3]));
}

__global__ void vq_finalize2(const double* __restrict__ lslots,
                             float* __restrict__ out) {
    double s = 0.0;
    for (int i = threadIdx.x; i < 512; i += 64) s += lslots[i];
    #pragma unroll
    for (int off = 32; off > 0; off >>= 1) s += __shfl_down(s, off);
    if (threadIdx.x == 0) {
        double m = s / 8388608.0;
        out[LOSS_OFF] = (float)(m + 0.25 * m);
    }
}

// ---------------- fallback (R5-validated fused path, used only if ws tiny) ----
__global__ void vq_zero(double* __restrict__ loss_acc) {
    if (threadIdx.x == 0) *loss_acc = 0.0;
}

__global__ __launch_bounds__(256) void vq_fused(const float* __restrict__ x_in,
                                                const float* __restrict__ weight,
                                                double* __restrict__ loss_acc,
                                                float* __restrict__ out) {
    __shared__ float w2s[NUM_K];
    for (int k = threadIdx.x; k < NUM_K; k += 256) {
        const float* wk = weight + k * DIM;
        float s;
        NP_SUMSQ64(wk, s);
        w2s[k] = s;
    }
    __syncthreads();

    const int n  = blockIdx.x * 256 + threadIdx.x;
    const int b  = n >> 12;
    const int hw = n & 4095;
    const float* xp = x_in + b * CHW + hw;
    float x[DIM];
    #pragma unroll
    for (int d = 0; d < DIM; ++d) x[d] = xp[d * HW];

    float A;
    NP_SUMSQ64(x, A);

    float best = 3.4e38f;
    int   bi   = 0;
    for (int k = 0; k < NUM_K; k += 4) {
        const float* w0 = weight + k * DIM;
        float m0 = 0.f, m1 = 0.f, m2 = 0.f, m3 = 0.f;
        #pragma unroll
        for (int d = 0; d < DIM; ++d) {
            float xd = x[d];
            m0 = __fmaf_rn(xd, w0[d],           m0);
            m1 = __fmaf_rn(xd, w0[DIM + d],     m1);
            m2 = __fmaf_rn(xd, w0[2 * DIM + d], m2);
            m3 = __fmaf_rn(xd, w0[3 * DIM + d], m3);
        }
        float d0 = __fadd_rn(__fsub_rn(A, __fmul_rn(2.0f, m0)), w2s[k]);
        float d1 = __fadd_rn(__fsub_rn(A, __fmul_rn(2.0f, m1)), w2s[k + 1]);
        float d2 = __fadd_rn(__fsub_rn(A, __fmul_rn(2.0f, m2)), w2s[k + 2]);
        float d3 = __fadd_rn(__fsub_rn(A, __fmul_rn(2.0f, m3)), w2s[k + 3]);
        if (d0 < best) { best = d0; bi = k; }
        if (d1 < best) { best = d1; bi = k + 1; }
        if (d2 < best) { best = d2; bi = k + 2; }
        if (d3 < best) { best = d3; bi = k + 3; }
    }
    const int idx = bi;

    out[IDX_OFF + n] = (float)idx;
    const float* qrow = weight + idx * DIM;
    float* oq = out + Q_OFF + b * CHW + hw;
    float lsum = 0.0f;
    #pragma unroll
    for (int d = 0; d < DIM; ++d) {
        float xd   = xp[d * HW];
        float diff = __fsub_rn(qrow[d], xd);
        oq[d * HW] = __fadd_rn(xd, diff);
        lsum = fmaf(diff, diff, lsum);
    }
    #pragma unroll
    for (int off = 32; off > 0; off >>= 1) lsum += __shfl_down(lsum, off);
    __shared__ float wsum[4];
    if ((threadIdx.x & 63) == 0) wsum[threadIdx.x >> 6] = lsum;
    __syncthreads();
    if (threadIdx.x == 0)
        atomicAdd(loss_acc, (double)((wsum[0] + wsum[1]) + (wsum[2] + wsum[3])));
}

__global__ void vq_finalize(const double* __restrict__ loss_acc,
                            float* __restrict__ out) {
    double m = *loss_acc / 8388608.0;
    out[LOSS_OFF] = (float)(m + 0.25 * m);
}

extern "C" void kernel_launch(void* const* d_in, const int* in_sizes, int n_in,
                              void* d_out, int out_size, void* d_ws, size_t ws_size,
                              hipStream_t stream) {
    const float* x = (const float*)d_in[0];    // inputs  [32,64,64,64] NCHW fp32
    const float* w = (const float*)d_in[1];    // weight  [512,64] fp32
    float* out = (float*)d_out;

    size_t need = (size_t)NCHUNK * N_ROWS * 8 + 512 * 8;
    if (ws_size >= need) {
        unsigned long long* keys = (unsigned long long*)d_ws;
        double* lslots = (double*)((char*)d_ws + (size_t)NCHUNK * N_ROWS * 8);
        vq_partial<<<512 * NCHUNK, 256, 0, stream>>>(x, w, keys);
        vq_emit<<<512, 256, 0, stream>>>(x, w, keys, lslots, out, NCHUNK);
        vq_finalize2<<<1, 64, 0, stream>>>(lslots, out);
    } else {
        double* loss_acc = (double*)d_ws;      // 8 bytes
        vq_zero<<<1, 64, 0, stream>>>(loss_acc);
        vq_fused<<<512, 256, 0, stream>>>(x, w, loss_acc, out);
        vq_finalize<<<1, 1, 0, stream>>>(loss_acc, out);
    }
}

// Round 8
// 214.890 us; speedup vs baseline: 1.1942x; 1.0661x over previous
//
#include <hip/hip_runtime.h>

typedef unsigned long long ull;

#define NUM_K   512
#define DIM     64
#define N_ROWS  (32 * 64 * 64)     // 131072 rows
#define HW      4096               // 64*64
#define CHW     (64 * 4096)        // per-batch stride (C*H*W)

// Output buffer float32, flat layout = reference return order:
//   [ discrete (131072) | quantized NCHW (8388608) | loss (1) ]
#define IDX_OFF  0
#define Q_OFF    N_ROWS
#define LOSS_OFF (N_ROWS + 32 * 64 * 4096)   // 8519680

#define RS      68     // LDS row stride (dwords): 16B-aligned, banks 4 apart per row
#define TILE_R  128
#define TILE_K  128
#define NSTAGE  4      // 4 x 128 codes = 512

// numpy pairwise_sum (n=64) of squares (validated bit-exact R5-R7)
#define NP_SUMSQ64(SRC, DST)                                                   \
    do {                                                                       \
        float r_[8];                                                           \
        _Pragma("unroll")                                                      \
        for (int j_ = 0; j_ < 8; ++j_) r_[j_] = __fmul_rn((SRC)[j_], (SRC)[j_]); \
        _Pragma("unroll")                                                      \
        for (int i_ = 8; i_ < 64; i_ += 8) {                                   \
            _Pragma("unroll")                                                  \
            for (int j_ = 0; j_ < 8; ++j_)                                     \
                r_[j_] = __fadd_rn(r_[j_], __fmul_rn((SRC)[i_ + j_], (SRC)[i_ + j_])); \
        }                                                                      \
        (DST) = __fadd_rn(__fadd_rn(__fadd_rn(r_[0], r_[1]), __fadd_rn(r_[2], r_[3])), \
                          __fadd_rn(__fadd_rn(r_[4], r_[5]), __fadd_rn(r_[6], r_[7]))); \
    } while (0)

// One fused kernel: 128 rows/block vs all 512 codes; register-tiled 8x8.
__global__ __launch_bounds__(256, 2) void vq_tile(const float* __restrict__ x_in,
                                                  const float* __restrict__ weight,
                                                  double* __restrict__ lslots,
                                                  float* __restrict__ out) {
    __shared__ float xlds[TILE_R * RS];    // 34816 B
    __shared__ float wlds[TILE_K * RS];    // 34816 B
    __shared__ float Arow[TILE_R];
    __shared__ float w2all[NUM_K];
    __shared__ int   ilds[TILE_R];
    __shared__ float wsum[4];

    const int tid     = threadIdx.x;
    const int rowbase = blockIdx.x * TILE_R;
    const int b       = rowbase >> 12;
    const int hw0     = rowbase & 4095;    // 128-aligned, same b for whole tile
    const float* xb   = x_in + (size_t)b * CHW + hw0;

    // ---- stage x tile [row][d] (coalesced float4 along rows, transpose-write) ----
    #pragma unroll
    for (int it = 0; it < 8; ++it) {
        int e = it * 256 + tid;
        int d = e >> 5, r4 = (e & 31) << 2;
        float4 v = *(const float4*)(xb + d * HW + r4);
        xlds[(r4 + 0) * RS + d] = v.x;
        xlds[(r4 + 1) * RS + d] = v.y;
        xlds[(r4 + 2) * RS + d] = v.z;
        xlds[(r4 + 3) * RS + d] = v.w;
    }
    // ---- stage w chunk 0 ----
    #pragma unroll
    for (int it = 0; it < 8; ++it) {
        int f = it * 256 + tid;
        int c = f >> 4, d4 = (f & 15) << 2;
        *(float4*)&wlds[c * RS + d4] = *(const float4*)(weight + c * DIM + d4);
    }
    // ---- ||w||^2 for all 512 codes (numpy-pairwise, from global/L2) ----
    #pragma unroll
    for (int cc = 0; cc < 2; ++cc) {
        int c = tid + cc * 256;
        const float* wk = weight + c * DIM;
        float s; NP_SUMSQ64(wk, s);
        w2all[c] = s;
    }
    __syncthreads();
    // ---- per-row A = np.sum(x*x) (numpy-pairwise, from xlds) ----
    if (tid < TILE_R) {
        const float* src = &xlds[tid * RS];
        float s; NP_SUMSQ64(src, s);
        Arow[tid] = s;
    }

    const int tr = tid >> 4;   // row-thread 0..15 (wave = 4 consecutive tr groups)
    const int tc = tid & 15;   // code-thread 0..15 (all 16 within each wave)

    float best[8];
    int   bidx[8];
    #pragma unroll
    for (int i = 0; i < 8; ++i) { best[i] = 3.4e38f; bidx[i] = 0; }

    for (int s = 0; s < NSTAGE; ++s) {
        if (s > 0) {
            __syncthreads();   // all waves done reading previous wlds
            const float* wb = weight + (size_t)(s * TILE_K) * DIM;
            #pragma unroll
            for (int it = 0; it < 8; ++it) {
                int f = it * 256 + tid;
                int c = f >> 4, d4 = (f & 15) << 2;
                *(float4*)&wlds[c * RS + d4] = *(const float4*)(wb + c * DIM + d4);
            }
        }
        __syncthreads();       // wlds (and Arow on s==0) visible

        // ---- 8x8 register tile GEMM over d ----
        float m[8][8];
        #pragma unroll
        for (int i = 0; i < 8; ++i)
            #pragma unroll
            for (int j = 0; j < 8; ++j) m[i][j] = 0.0f;

        for (int q = 0; q < 16; ++q) {
            const int d = q * 4;
            float4 xa[8];
            #pragma unroll
            for (int i = 0; i < 8; ++i)
                xa[i] = *(const float4*)&xlds[(tr + 16 * i) * RS + d];
            #pragma unroll
            for (int j = 0; j < 8; ++j) {
                float4 wv = *(const float4*)&wlds[(tc + 16 * j) * RS + d];
                #pragma unroll
                for (int i = 0; i < 8; ++i) {
                    // sequential d-chain per (row,code): OpenBLAS sgemm semantics
                    m[i][j] = __fmaf_rn(xa[i].x, wv.x, m[i][j]);
                    m[i][j] = __fmaf_rn(xa[i].y, wv.y, m[i][j]);
                    m[i][j] = __fmaf_rn(xa[i].z, wv.z, m[i][j]);
                    m[i][j] = __fmaf_rn(xa[i].w, wv.w, m[i][j]);
                }
            }
        }

        // ---- per-stage epilogue: dist + carried argmin (idx ascending over (s,j)) ----
        const int k0 = s * TILE_K;
        #pragma unroll
        for (int i = 0; i < 8; ++i) {
            float Ai = Arow[tr + 16 * i];
            #pragma unroll
            for (int j = 0; j < 8; ++j) {
                int code = k0 + tc + 16 * j;
                float dist = __fadd_rn(__fsub_rn(Ai, __fmul_rn(2.0f, m[i][j])),
                                       w2all[code]);
                if (dist < best[i]) { best[i] = dist; bidx[i] = code; }
            }
        }
    }

    // ---- cross-lane argmin per row: u64 key butterfly over the 16 tc lanes ----
    #pragma unroll
    for (int i = 0; i < 8; ++i) {
        ull key = ((ull)__float_as_uint(best[i]) << 32) | (unsigned)bidx[i];
        #pragma unroll
        for (int mk = 1; mk <= 8; mk <<= 1) {
            ull o = __shfl_xor(key, mk);
            if (o < key) key = o;
        }
        if (tc == 0) {
            int row = tr + 16 * i;
            int idx = (int)(key & 0xffffffffu);
            ilds[row] = idx;
            out[IDX_OFF + rowbase + row] = (float)idx;
        }
    }
    __syncthreads();   // ilds visible

    // ---- quantize epilogue + loss (x from xlds, w gathered from L2) ----
    float lsum = 0.0f;
    float* oqb = out + Q_OFF + (size_t)b * CHW + hw0;
    #pragma unroll
    for (int it = 0; it < 8; ++it) {
        int e = it * 256 + tid;
        int d = e >> 5, r4 = (e & 31) << 2;
        float o[4];
        #pragma unroll
        for (int i2 = 0; i2 < 4; ++i2) {
            int row = r4 + i2;
            float xd   = xlds[row * RS + d];
            float wq   = weight[ilds[row] * DIM + d];
            float diff = __fsub_rn(wq, xd);     // fl(q - x)
            o[i2] = __fadd_rn(xd, diff);        // straight-through
            lsum = fmaf(diff, diff, lsum);      // loss tol 2% — fused ok
        }
        *(float4*)(oqb + d * HW + r4) = make_float4(o[0], o[1], o[2], o[3]);
    }

    #pragma unroll
    for (int off = 32; off > 0; off >>= 1) lsum += __shfl_down(lsum, off);
    if ((tid & 63) == 0) wsum[tid >> 6] = lsum;
    __syncthreads();
    if (tid == 0)
        lslots[blockIdx.x] = (double)((wsum[0] + wsum[1]) + (wsum[2] + wsum[3]));
}

__global__ void vq_finalize3(const double* __restrict__ lslots,
                             float* __restrict__ out) {
    double s = 0.0;
    for (int i = threadIdx.x; i < 1024; i += 64) s += lslots[i];
    #pragma unroll
    for (int off = 32; off > 0; off >>= 1) s += __shfl_down(s, off);
    if (threadIdx.x == 0) {
        double m = s / 8388608.0;
        out[LOSS_OFF] = (float)(m + 0.25 * m);   // q_latent + 0.25 * e_latent
    }
}

// ---------------- fallback (R5-validated fused path, used only if ws tiny) ----
__global__ void vq_zero(double* __restrict__ loss_acc) {
    if (threadIdx.x == 0) *loss_acc = 0.0;
}

__global__ __launch_bounds__(256) void vq_fused(const float* __restrict__ x_in,
                                                const float* __restrict__ weight,
                                                double* __restrict__ loss_acc,
                                                float* __restrict__ out) {
    __shared__ float w2s[NUM_K];
    for (int k = threadIdx.x; k < NUM_K; k += 256) {
        const float* wk = weight + k * DIM;
        float s; NP_SUMSQ64(wk, s);
        w2s[k] = s;
    }
    __syncthreads();

    const int n  = blockIdx.x * 256 + threadIdx.x;
    const int b  = n >> 12;
    const int hw = n & 4095;
    const float* xp = x_in + b * CHW + hw;
    float x[DIM];
    #pragma unroll
    for (int d = 0; d < DIM; ++d) x[d] = xp[d * HW];

    float A; NP_SUMSQ64(x, A);

    float best = 3.4e38f;
    int   bi   = 0;
    for (int k = 0; k < NUM_K; k += 4) {
        const float* w0 = weight + k * DIM;
        float m0 = 0.f, m1 = 0.f, m2 = 0.f, m3 = 0.f;
        #pragma unroll
        for (int d = 0; d < DIM; ++d) {
            float xd = x[d];
            m0 = __fmaf_rn(xd, w0[d],           m0);
            m1 = __fmaf_rn(xd, w0[DIM + d],     m1);
            m2 = __fmaf_rn(xd, w0[2 * DIM + d], m2);
            m3 = __fmaf_rn(xd, w0[3 * DIM + d], m3);
        }
        float d0 = __fadd_rn(__fsub_rn(A, __fmul_rn(2.0f, m0)), w2s[k]);
        float d1 = __fadd_rn(__fsub_rn(A, __fmul_rn(2.0f, m1)), w2s[k + 1]);
        float d2 = __fadd_rn(__fsub_rn(A, __fmul_rn(2.0f, m2)), w2s[k + 2]);
        float d3 = __fadd_rn(__fsub_rn(A, __fmul_rn(2.0f, m3)), w2s[k + 3]);
        if (d0 < best) { best = d0; bi = k; }
        if (d1 < best) { best = d1; bi = k + 1; }
        if (d2 < best) { best = d2; bi = k + 2; }
        if (d3 < best) { best = d3; bi = k + 3; }
    }
    const int idx = bi;

    out[IDX_OFF + n] = (float)idx;
    const float* qrow = weight + idx * DIM;
    float* oq = out + Q_OFF + b * CHW + hw;
    float lsum = 0.0f;
    #pragma unroll
    for (int d = 0; d < DIM; ++d) {
        float xd   = xp[d * HW];
        float diff = __fsub_rn(qrow[d], xd);
        oq[d * HW] = __fadd_rn(xd, diff);
        lsum = fmaf(diff, diff, lsum);
    }
    #pragma unroll
    for (int off = 32; off > 0; off >>= 1) lsum += __shfl_down(lsum, off);
    __shared__ float wsum[4];
    if ((threadIdx.x & 63) == 0) wsum[threadIdx.x >> 6] = lsum;
    __syncthreads();
    if (threadIdx.x == 0)
        atomicAdd(loss_acc, (double)((wsum[0] + wsum[1]) + (wsum[2] + wsum[3])));
}

__global__ void vq_finalize(const double* __restrict__ loss_acc,
                            float* __restrict__ out) {
    double m = *loss_acc / 8388608.0;
    out[LOSS_OFF] = (float)(m + 0.25 * m);
}

extern "C" void kernel_launch(void* const* d_in, const int* in_sizes, int n_in,
                              void* d_out, int out_size, void* d_ws, size_t ws_size,
                              hipStream_t stream) {
    const float* x = (const float*)d_in[0];    // inputs  [32,64,64,64] NCHW fp32
    const float* w = (const float*)d_in[1];    // weight  [512,64] fp32
    float* out = (float*)d_out;

    if (ws_size >= 1024 * sizeof(double)) {
        double* lslots = (double*)d_ws;        // 8 KB: per-block loss partials
        vq_tile<<<N_ROWS / TILE_R, 256, 0, stream>>>(x, w, lslots, out);
        vq_finalize3<<<1, 64, 0, stream>>>(lslots, out);
    } else {
        double* loss_acc = (double*)d_ws;      // 8 bytes
        vq_zero<<<1, 64, 0, stream>>>(loss_acc);
        vq_fused<<<512, 256, 0, stream>>>(x, w, loss_acc, out);
        vq_finalize<<<1, 1, 0, stream>>>(loss_acc, out);
    }
}